// Round 4
// baseline (715.002 us; speedup 1.0000x reference)
//
#include <hip/hip_runtime.h>
#include <hip/hip_fp16.h>

#define FEAT 48
#define CH 12            // 12 active lanes per node row (4 fp16 feats each)
#define UST 16           // u-state row stride in uint2 (128B padded rows)
#define STEPS 10
#define K 16             // histogram privatization copies
constexpr float LAM   = 0.9f;
constexpr float OMLAM = 0.1f;

#define SCB 1024
#define SCE 4

// --- setup kernels -------------------------------------------------------

// privatized histograms: copy k = (e>>8)&(K-1); slot_local via atomic return
__global__ void count_kernel(const int* __restrict__ row, const int* __restrict__ col,
                             int* __restrict__ deg, int* __restrict__ cnt,
                             unsigned short* __restrict__ slot,
                             const int* __restrict__ mask, int* __restrict__ winner,
                             int E, int M, int N) {
    int e = blockIdx.x * blockDim.x + threadIdx.x;
    if (e < E) {
        int k = (e >> 8) & (K - 1);
        atomicAdd(&deg[k * N + col[e]], 1);
        slot[e] = (unsigned short)atomicAdd(&cnt[k * N + row[e]], 1);
    }
    if (e < M) atomicMax(&winner[mask[e]], e);   // numpy last-write-wins
}

// per node: sum deg copies -> dinv; exclusive-prefix cnt copies in place;
// emit rowcount for the off-scan
__global__ void base_kernel(int* __restrict__ deg, int* __restrict__ cnt,
                            float* __restrict__ dinv, int* __restrict__ rowcount, int N) {
    int r = blockIdx.x * blockDim.x + threadIdx.x;
    if (r >= N) return;
    int ds = 0;
    #pragma unroll
    for (int k = 0; k < K; ++k) ds += deg[k * N + r];
    dinv[r] = (float)(1.0 / sqrt((double)ds));   // deg >= 1 guaranteed
    int run = 0;
    #pragma unroll
    for (int k = 0; k < K; ++k) {
        int v = cnt[k * N + r];
        cnt[k * N + r] = run;
        run += v;
    }
    rowcount[r] = run;
}

// hierarchical exclusive scan over rowcount -> off
__global__ void scan_part(const int* __restrict__ cnt, int* __restrict__ off,
                          int* __restrict__ bsum, int n) {
    __shared__ int part[SCB];
    int tid  = threadIdx.x;
    int base = blockIdx.x * (SCB * SCE) + tid * SCE;
    int v[SCE];
    int s = 0;
    #pragma unroll
    for (int k = 0; k < SCE; ++k) {
        int i = base + k;
        v[k] = (i < n) ? cnt[i] : 0;
        s += v[k];
    }
    part[tid] = s;
    __syncthreads();
    for (int d = 1; d < SCB; d <<= 1) {
        int tv = (tid >= d) ? part[tid - d] : 0;
        __syncthreads();
        part[tid] += tv;
        __syncthreads();
    }
    int run = (tid ? part[tid - 1] : 0);
    #pragma unroll
    for (int k = 0; k < SCE; ++k) {
        int i = base + k;
        if (i < n) off[i] = run;
        run += v[k];
    }
    if (tid == SCB - 1) bsum[blockIdx.x] = part[SCB - 1];
}

__global__ void scan_fixup(int* __restrict__ off, const int* __restrict__ bsum,
                           int nblocks, int n) {
    __shared__ int addv;
    int tid = threadIdx.x;
    if (tid == 0) {
        int s = 0;
        for (int b = 0; b < (int)blockIdx.x; ++b) s += bsum[b];
        addv = s;
        if (blockIdx.x == 0) {
            int tot = 0;
            for (int b = 0; b < nblocks; ++b) tot += bsum[b];
            off[n] = tot;
        }
    }
    __syncthreads();
    if (blockIdx.x == 0) return;
    int base = blockIdx.x * (SCB * SCE) + tid * SCE;
    #pragma unroll
    for (int k = 0; k < SCE; ++k) {
        int i = base + k;
        if (i < n) off[i] += addv;
    }
}

// atomic-free CSR fill; copy k reconstructed from e
__global__ void fill_kernel(const int* __restrict__ row, const int* __restrict__ col,
                            const int* __restrict__ off, const int* __restrict__ cnt,
                            const unsigned short* __restrict__ slot,
                            int* __restrict__ csr_col, int E, int N) {
    int e = blockIdx.x * blockDim.x + threadIdx.x;
    if (e < E) {
        int r = row[e];
        int k = (e >> 8) & (K - 1);
        csr_col[off[r] + cnt[k * N + r] + (int)slot[e]] = col[e];
    }
}

// fused: G = winner>=0 ? Y[winner] : Z ; u0 = fp16(dinv * G), padded rows
__global__ void prep_kernel(const float4* __restrict__ Z4, const float4* __restrict__ Y4,
                            const int* __restrict__ winner, const float* __restrict__ dinv,
                            float4* __restrict__ G4, uint2* __restrict__ u0, int N) {
    int t = blockIdx.x * blockDim.x + threadIdx.x;
    if (t >= N * CH) return;
    int r = t / CH, q = t - r * CH;
    int w = winner[r];
    float4 g = (w >= 0) ? Y4[(size_t)w * CH + q] : Z4[t];
    G4[t] = g;
    float d = dinv[r];
    __half2 h0 = __floats2half2_rn(d * g.x, d * g.y);
    __half2 h1 = __floats2half2_rn(d * g.z, d * g.w);
    u0[(size_t)r * UST + q] = make_uint2(__builtin_bit_cast(unsigned int, h0),
                                         __builtin_bit_cast(unsigned int, h1));
}

// --- diffusion step ------------------------------------------------------
// S_r = sum_{c in N(r)} u[c];  u_new = lam*dinv^2*S + 0.1*u0  (steps 0..8)
//                              x_out = lam*dinv  *S + 0.1*G   (final step)
// u rows padded to 128B: every gather is exactly one cache line.
template<bool LAST>
__global__ void diffuse_kernel(const uint2* __restrict__ up, const uint2* __restrict__ u0,
                               const float* __restrict__ dinv, const float4* __restrict__ G4,
                               const int* __restrict__ off, const int* __restrict__ cols,
                               uint2* __restrict__ uout, float4* __restrict__ xout, int N) {
    int t = blockIdx.x * blockDim.x + threadIdx.x;
    if (t >= N * CH) return;
    int r = t / CH, q = t - r * CH;
    int j0 = off[r], j1 = off[r + 1];
    float ax = 0.f, ay = 0.f, az = 0.f, aw = 0.f;
    int c = (j0 < j1) ? cols[j0] : 0;
    for (int j = j0; j < j1; ++j) {
        int cn = (j + 1 < j1) ? cols[j + 1] : 0;   // prefetch next col
        uint2 v = up[(size_t)c * UST + q];
        float2 f0 = __half22float2(__builtin_bit_cast(__half2, v.x));
        float2 f1 = __half22float2(__builtin_bit_cast(__half2, v.y));
        ax += f0.x; ay += f0.y; az += f1.x; aw += f1.y;
        c = cn;
    }
    float d = dinv[r];
    if (LAST) {
        float4 g = G4[t];
        float4 o;
        float s = LAM * d;
        o.x = fmaf(s, ax, OMLAM * g.x);
        o.y = fmaf(s, ay, OMLAM * g.y);
        o.z = fmaf(s, az, OMLAM * g.z);
        o.w = fmaf(s, aw, OMLAM * g.w);
        xout[t] = o;
    } else {
        float a = LAM * d * d;
        uint2 z = u0[(size_t)r * UST + q];
        float2 b0 = __half22float2(__builtin_bit_cast(__half2, z.x));
        float2 b1 = __half22float2(__builtin_bit_cast(__half2, z.y));
        __half2 h0 = __floats2half2_rn(fmaf(a, ax, OMLAM * b0.x),
                                       fmaf(a, ay, OMLAM * b0.y));
        __half2 h1 = __floats2half2_rn(fmaf(a, az, OMLAM * b1.x),
                                       fmaf(a, aw, OMLAM * b1.y));
        uout[(size_t)r * UST + q] = make_uint2(__builtin_bit_cast(unsigned int, h0),
                                               __builtin_bit_cast(unsigned int, h1));
    }
}

// --- launch --------------------------------------------------------------

extern "C" void kernel_launch(void* const* d_in, const int* in_sizes, int n_in,
                              void* d_out, int out_size, void* d_ws, size_t ws_size,
                              hipStream_t stream) {
    const float* Z    = (const float*)d_in[0];
    const float* Y    = (const float*)d_in[1];
    const int*   mask = (const int*)d_in[2];
    const int*   ei   = (const int*)d_in[3];

    const int N = in_sizes[0] / FEAT;
    const int M = in_sizes[2];
    const int E = in_sizes[3] / 2;
    const int* row = ei;
    const int* col = ei + E;

    char* ws = (char*)d_ws;
    size_t pos = 0;
    auto alloc = [&](size_t bytes) -> void* {
        void* p = ws + pos;
        pos = (pos + bytes + 255) & ~(size_t)255;
        return p;
    };
    float* G        = (float*)alloc((size_t)N * FEAT * 4);
    uint2* u0       = (uint2*)alloc((size_t)N * UST * 8);
    uint2* ua       = (uint2*)alloc((size_t)N * UST * 8);
    uint2* ub       = (uint2*)alloc((size_t)N * UST * 8);
    int*   deg      = (int*)  alloc((size_t)K * N * 4);
    int*   cnt      = (int*)  alloc((size_t)K * N * 4);
    float* dinv     = (float*)alloc((size_t)N * 4);
    int*   rowcount = (int*)  alloc((size_t)N * 4);
    int*   off      = (int*)  alloc((size_t)(N + 1) * 4);
    int*   winner   = (int*)  alloc((size_t)N * 4);
    unsigned short* slot = (unsigned short*)alloc((size_t)E * 2);
    int*   csr      = (int*)  alloc((size_t)E * 4);
    int*   bsum     = (int*)  alloc((size_t)1024 * 4);

    hipMemsetAsync(deg,    0,    (size_t)K * N * 4, stream);
    hipMemsetAsync(cnt,    0,    (size_t)K * N * 4, stream);
    hipMemsetAsync(winner, 0xFF, (size_t)N * 4, stream);

    const int B = 256;
    count_kernel<<<(E + B - 1) / B, B, 0, stream>>>(row, col, deg, cnt, slot,
                                                    mask, winner, E, M, N);
    base_kernel <<<(N + B - 1) / B, B, 0, stream>>>(deg, cnt, dinv, rowcount, N);

    const int scan_nb = (N + SCB * SCE - 1) / (SCB * SCE);
    scan_part <<<scan_nb, SCB, 0, stream>>>(rowcount, off, bsum, N);
    scan_fixup<<<scan_nb, SCB, 0, stream>>>(off, bsum, scan_nb, N);

    fill_kernel<<<(E + B - 1) / B, B, 0, stream>>>(row, col, off, cnt, slot, csr, E, N);

    const int nt = N * CH;
    prep_kernel<<<(nt + B - 1) / B, B, 0, stream>>>((const float4*)Z, (const float4*)Y,
                                                    winner, dinv, (float4*)G, u0, N);

    // steps 0..8 fp16 ping-pong, step 9 -> f32 d_out
    const uint2* src = u0;
    uint2* bufs[2] = { ua, ub };
    for (int it = 0; it < STEPS - 1; ++it) {
        uint2* dst = bufs[it & 1];
        diffuse_kernel<false><<<(nt + B - 1) / B, B, 0, stream>>>(
            src, u0, dinv, (const float4*)G, off, csr, dst, nullptr, N);
        src = dst;
    }
    diffuse_kernel<true><<<(nt + B - 1) / B, B, 0, stream>>>(
        src, u0, dinv, (const float4*)G, off, csr, nullptr, (float4*)d_out, N);
}

// Round 5
// 561.053 us; speedup vs baseline: 1.2744x; 1.2744x over previous
//
#include <hip/hip_runtime.h>
#include <hip/hip_fp16.h>

#define FEAT 48
#define CH 12            // 12 lanes per node row, 4 fp16 feats (8B) each; 96B rows
#define STEPS 10
constexpr float LAM   = 0.9f;
constexpr float OMLAM = 0.1f;

#define SCB 1024
#define SCE 4

// --- setup kernels -------------------------------------------------------

// in-degree (by col), out-count+slot (by row), winner pass
__global__ void count_kernel(const int* __restrict__ row, const int* __restrict__ col,
                             int* __restrict__ deg, int* __restrict__ cnt,
                             int* __restrict__ slot,
                             const int* __restrict__ mask, int* __restrict__ winner,
                             int E, int M) {
    int e = blockIdx.x * blockDim.x + threadIdx.x;
    if (e < E) {
        atomicAdd(&deg[col[e]], 1);
        slot[e] = atomicAdd(&cnt[row[e]], 1);
    }
    if (e < M) atomicMax(&winner[mask[e]], e);   // numpy last-write-wins
}

__global__ void dinv_kernel(const int* __restrict__ deg, float* __restrict__ dinv, int N) {
    int v = blockIdx.x * blockDim.x + threadIdx.x;
    if (v < N) dinv[v] = (float)(1.0 / sqrt((double)deg[v]));   // deg >= 1
}

// hierarchical exclusive scan
__global__ void scan_part(const int* __restrict__ cnt, int* __restrict__ off,
                          int* __restrict__ bsum, int n) {
    __shared__ int part[SCB];
    int tid  = threadIdx.x;
    int base = blockIdx.x * (SCB * SCE) + tid * SCE;
    int v[SCE];
    int s = 0;
    #pragma unroll
    for (int k = 0; k < SCE; ++k) {
        int i = base + k;
        v[k] = (i < n) ? cnt[i] : 0;
        s += v[k];
    }
    part[tid] = s;
    __syncthreads();
    for (int d = 1; d < SCB; d <<= 1) {
        int tv = (tid >= d) ? part[tid - d] : 0;
        __syncthreads();
        part[tid] += tv;
        __syncthreads();
    }
    int run = (tid ? part[tid - 1] : 0);
    #pragma unroll
    for (int k = 0; k < SCE; ++k) {
        int i = base + k;
        if (i < n) off[i] = run;
        run += v[k];
    }
    if (tid == SCB - 1) bsum[blockIdx.x] = part[SCB - 1];
}

__global__ void scan_fixup(int* __restrict__ off, const int* __restrict__ bsum,
                           int nblocks, int n) {
    __shared__ int addv;
    int tid = threadIdx.x;
    if (tid == 0) {
        int s = 0;
        for (int b = 0; b < (int)blockIdx.x; ++b) s += bsum[b];
        addv = s;
        if (blockIdx.x == 0) {
            int tot = 0;
            for (int b = 0; b < nblocks; ++b) tot += bsum[b];
            off[n] = tot;
        }
    }
    __syncthreads();
    if (blockIdx.x == 0) return;
    int base = blockIdx.x * (SCB * SCE) + tid * SCE;
    #pragma unroll
    for (int k = 0; k < SCE; ++k) {
        int i = base + k;
        if (i < n) off[i] += addv;
    }
}

// atomic-free CSR fill (col only; weights folded into u = dinv * x)
__global__ void fill_kernel(const int* __restrict__ row, const int* __restrict__ col,
                            const int* __restrict__ off, const int* __restrict__ slot,
                            int* __restrict__ csr_col, int E) {
    int e = blockIdx.x * blockDim.x + threadIdx.x;
    if (e < E) csr_col[off[row[e]] + slot[e]] = col[e];
}

// fused: G = winner>=0 ? Y[winner] : Z ; u0 = fp16(dinv * G)
__global__ void prep_kernel(const float4* __restrict__ Z4, const float4* __restrict__ Y4,
                            const int* __restrict__ winner, const float* __restrict__ dinv,
                            float4* __restrict__ G4, uint2* __restrict__ u0, int N) {
    int t = blockIdx.x * blockDim.x + threadIdx.x;
    if (t >= N * CH) return;
    int r = t / CH, q = t - r * CH;
    int w = winner[r];
    float4 g = (w >= 0) ? Y4[(size_t)w * CH + q] : Z4[t];
    G4[t] = g;
    float d = dinv[r];
    __half2 h0 = __floats2half2_rn(d * g.x, d * g.y);
    __half2 h1 = __floats2half2_rn(d * g.z, d * g.w);
    u0[t] = make_uint2(__builtin_bit_cast(unsigned int, h0),
                       __builtin_bit_cast(unsigned int, h1));
}

// --- diffusion step ------------------------------------------------------
// S_r = sum_{c in N(r)} u[c];  u_new = lam*dinv^2*S + 0.1*u0  (steps 0..8)
//                              x_out = lam*dinv  *S + 0.1*G   (final step)
// 4-wide unrolled gathers: 4 independent u-row loads in flight per thread.
template<bool LAST>
__global__ void diffuse_kernel(const uint2* __restrict__ up, const uint2* __restrict__ u0,
                               const float* __restrict__ dinv, const float4* __restrict__ G4,
                               const int* __restrict__ off, const int* __restrict__ cols,
                               uint2* __restrict__ uout, float4* __restrict__ xout, int N) {
    int t = blockIdx.x * blockDim.x + threadIdx.x;
    if (t >= N * CH) return;
    int r = t / CH, q = t - r * CH;
    int j0 = off[r], j1 = off[r + 1];
    float ax = 0.f, ay = 0.f, az = 0.f, aw = 0.f;

    int j = j0;
    for (; j + 4 <= j1; j += 4) {
        int c0 = cols[j], c1 = cols[j + 1], c2 = cols[j + 2], c3 = cols[j + 3];
        uint2 v0 = up[(size_t)c0 * CH + q];
        uint2 v1 = up[(size_t)c1 * CH + q];
        uint2 v2 = up[(size_t)c2 * CH + q];
        uint2 v3 = up[(size_t)c3 * CH + q];
        float2 f;
        f = __half22float2(__builtin_bit_cast(__half2, v0.x)); ax += f.x; ay += f.y;
        f = __half22float2(__builtin_bit_cast(__half2, v0.y)); az += f.x; aw += f.y;
        f = __half22float2(__builtin_bit_cast(__half2, v1.x)); ax += f.x; ay += f.y;
        f = __half22float2(__builtin_bit_cast(__half2, v1.y)); az += f.x; aw += f.y;
        f = __half22float2(__builtin_bit_cast(__half2, v2.x)); ax += f.x; ay += f.y;
        f = __half22float2(__builtin_bit_cast(__half2, v2.y)); az += f.x; aw += f.y;
        f = __half22float2(__builtin_bit_cast(__half2, v3.x)); ax += f.x; ay += f.y;
        f = __half22float2(__builtin_bit_cast(__half2, v3.y)); az += f.x; aw += f.y;
    }
    // remainder (0..3): loads are independent of acc, compiler can hoist
    if (j < j1) {
        int c0 = cols[j];
        int c1 = (j + 1 < j1) ? cols[j + 1] : c0;
        int c2 = (j + 2 < j1) ? cols[j + 2] : c0;
        uint2 v0 = up[(size_t)c0 * CH + q];
        uint2 v1 = up[(size_t)c1 * CH + q];
        uint2 v2 = up[(size_t)c2 * CH + q];
        float2 f;
        f = __half22float2(__builtin_bit_cast(__half2, v0.x)); ax += f.x; ay += f.y;
        f = __half22float2(__builtin_bit_cast(__half2, v0.y)); az += f.x; aw += f.y;
        if (j + 1 < j1) {
            f = __half22float2(__builtin_bit_cast(__half2, v1.x)); ax += f.x; ay += f.y;
            f = __half22float2(__builtin_bit_cast(__half2, v1.y)); az += f.x; aw += f.y;
        }
        if (j + 2 < j1) {
            f = __half22float2(__builtin_bit_cast(__half2, v2.x)); ax += f.x; ay += f.y;
            f = __half22float2(__builtin_bit_cast(__half2, v2.y)); az += f.x; aw += f.y;
        }
    }

    float d = dinv[r];
    if (LAST) {
        float4 g = G4[t];
        float4 o;
        float s = LAM * d;
        o.x = fmaf(s, ax, OMLAM * g.x);
        o.y = fmaf(s, ay, OMLAM * g.y);
        o.z = fmaf(s, az, OMLAM * g.z);
        o.w = fmaf(s, aw, OMLAM * g.w);
        xout[t] = o;
    } else {
        float a = LAM * d * d;
        uint2 z = u0[t];
        float2 b0 = __half22float2(__builtin_bit_cast(__half2, z.x));
        float2 b1 = __half22float2(__builtin_bit_cast(__half2, z.y));
        __half2 h0 = __floats2half2_rn(fmaf(a, ax, OMLAM * b0.x),
                                       fmaf(a, ay, OMLAM * b0.y));
        __half2 h1 = __floats2half2_rn(fmaf(a, az, OMLAM * b1.x),
                                       fmaf(a, aw, OMLAM * b1.y));
        uout[t] = make_uint2(__builtin_bit_cast(unsigned int, h0),
                             __builtin_bit_cast(unsigned int, h1));
    }
}

// --- launch --------------------------------------------------------------

extern "C" void kernel_launch(void* const* d_in, const int* in_sizes, int n_in,
                              void* d_out, int out_size, void* d_ws, size_t ws_size,
                              hipStream_t stream) {
    const float* Z    = (const float*)d_in[0];
    const float* Y    = (const float*)d_in[1];
    const int*   mask = (const int*)d_in[2];
    const int*   ei   = (const int*)d_in[3];

    const int N = in_sizes[0] / FEAT;
    const int M = in_sizes[2];
    const int E = in_sizes[3] / 2;
    const int* row = ei;
    const int* col = ei + E;

    char* ws = (char*)d_ws;
    size_t pos = 0;
    auto alloc = [&](size_t bytes) -> void* {
        void* p = ws + pos;
        pos = (pos + bytes + 255) & ~(size_t)255;
        return p;
    };
    float* G      = (float*)alloc((size_t)N * FEAT * 4);
    uint2* u0     = (uint2*)alloc((size_t)N * CH * 8);
    uint2* ua     = (uint2*)alloc((size_t)N * CH * 8);
    uint2* ub     = (uint2*)alloc((size_t)N * CH * 8);
    int*   deg    = (int*)  alloc((size_t)N * 4);
    float* dinv   = (float*)alloc((size_t)N * 4);
    int*   cnt    = (int*)  alloc((size_t)N * 4);
    int*   off    = (int*)  alloc((size_t)(N + 1) * 4);
    int*   winner = (int*)  alloc((size_t)N * 4);
    int*   slot   = (int*)  alloc((size_t)E * 4);
    int*   csr    = (int*)  alloc((size_t)E * 4);
    int*   bsum   = (int*)  alloc((size_t)1024 * 4);

    hipMemsetAsync(deg,    0,    (size_t)N * 4, stream);
    hipMemsetAsync(cnt,    0,    (size_t)N * 4, stream);
    hipMemsetAsync(winner, 0xFF, (size_t)N * 4, stream);

    const int B = 256;
    count_kernel<<<(E + B - 1) / B, B, 0, stream>>>(row, col, deg, cnt, slot,
                                                    mask, winner, E, M);
    dinv_kernel <<<(N + B - 1) / B, B, 0, stream>>>(deg, dinv, N);

    const int nt = N * CH;
    prep_kernel<<<(nt + B - 1) / B, B, 0, stream>>>((const float4*)Z, (const float4*)Y,
                                                    winner, dinv, (float4*)G, u0, N);

    const int scan_nb = (N + SCB * SCE - 1) / (SCB * SCE);
    scan_part <<<scan_nb, SCB, 0, stream>>>(cnt, off, bsum, N);
    scan_fixup<<<scan_nb, SCB, 0, stream>>>(off, bsum, scan_nb, N);

    fill_kernel<<<(E + B - 1) / B, B, 0, stream>>>(row, col, off, slot, csr, E);

    // steps 0..8 fp16 ping-pong, step 9 -> f32 d_out
    const uint2* src = u0;
    uint2* bufs[2] = { ua, ub };
    for (int it = 0; it < STEPS - 1; ++it) {
        uint2* dst = bufs[it & 1];
        diffuse_kernel<false><<<(nt + B - 1) / B, B, 0, stream>>>(
            src, u0, dinv, (const float4*)G, off, csr, dst, nullptr, N);
        src = dst;
    }
    diffuse_kernel<true><<<(nt + B - 1) / B, B, 0, stream>>>(
        src, u0, dinv, (const float4*)G, off, csr, nullptr, (float4*)d_out, N);
}